// Round 3
// baseline (1308.799 us; speedup 1.0000x reference)
//
#include <hip/hip_runtime.h>
#include <hip/hip_bf16.h>

#define DD 4096
#define MM 4096
#define SS 2048
#define HH 32
#define HDD 128
#define NT 64  // GEMM K-tiles of 64

typedef unsigned short u16;
typedef __attribute__((ext_vector_type(8))) __bf16 bf16x8;
typedef __attribute__((ext_vector_type(4))) float f32x4;
typedef __attribute__((ext_vector_type(4))) float float4v;
typedef __attribute__((ext_vector_type(8))) unsigned short ushort8;
typedef __attribute__((ext_vector_type(4))) unsigned int uint4v;

__device__ __forceinline__ u16 f2bf(float f) {
  union { float f; unsigned u; } v; v.f = f;
  unsigned u = v.u;
  return (u16)((u + 0x7fffu + ((u >> 16) & 1u)) >> 16);
}
__device__ __forceinline__ float bf2f(u16 s) {
  union { unsigned u; float f; } v; v.u = ((unsigned)s) << 16;
  return v.f;
}
__device__ __forceinline__ f32x4 zero4() { f32x4 z = {0.f, 0.f, 0.f, 0.f}; return z; }

__device__ __forceinline__ void gl_lds16(const u16* g, u16* l) {
  __builtin_amdgcn_global_load_lds((__attribute__((address_space(1))) void*)(g),
                                   (__attribute__((address_space(3))) void*)(l), 16, 0, 0);
}

// ---------------- f32 -> bf16 convert (x) ----------------
__global__ __launch_bounds__(256) void k_cvt(const float* __restrict__ in,
                                             u16* __restrict__ out, int n8) {
  int i = blockIdx.x * blockDim.x + threadIdx.x;
  if (i >= n8) return;
  size_t o = (size_t)i * 8;
  float4v a = *(const float4v*)(in + o);
  float4v b = *(const float4v*)(in + o + 4);
  ushort8 v;
  v[0] = f2bf(a[0]); v[1] = f2bf(a[1]); v[2] = f2bf(a[2]); v[3] = f2bf(a[3]);
  v[4] = f2bf(b[0]); v[5] = f2bf(b[1]); v[6] = f2bf(b[2]); v[7] = f2bf(b[3]);
  *(ushort8*)(out + o) = v;
}

// ---------------- weight transpose + convert: out[n][k] = W[k][n] ----------------
__global__ __launch_bounds__(256) void k_wt(const float* __restrict__ W0,
                                            const float* __restrict__ W1,
                                            const float* __restrict__ W2,
                                            const float* __restrict__ W3,
                                            u16* __restrict__ out) {
  const float* W = blockIdx.z == 0 ? W0 : blockIdx.z == 1 ? W1 : blockIdx.z == 2 ? W2 : W3;
  u16* O = out + (size_t)blockIdx.z * DD * DD;
  __shared__ u16 t[64][65];
  int k0 = blockIdx.x * 64, n0 = blockIdx.y * 64;
  int tx = threadIdx.x, ty = threadIdx.y;  // (64,4)
#pragma unroll
  for (int i = 0; i < 16; ++i) {
    int kk = ty + i * 4;
    t[tx][kk] = f2bf(W[(size_t)(k0 + kk) * DD + n0 + tx]);
  }
  __syncthreads();
#pragma unroll
  for (int i = 0; i < 16; ++i) {
    int nn = ty + i * 4;
    O[(size_t)(n0 + nn) * DD + k0 + tx] = t[nn][tx];
  }
}

// ---------------- 256x256 8-phase bf16 GEMM (m201 template) ----------------
#define MFMA16(QM, QN)                                                             \
  _Pragma("unroll") for (int kk = 0; kk < 2; ++kk)                                 \
  _Pragma("unroll") for (int mi = 0; mi < 4; ++mi)                                 \
  _Pragma("unroll") for (int ni = 0; ni < 2; ++ni)                                 \
      acc[(QM)*4 + mi][(QN)*2 + ni] = __builtin_amdgcn_mfma_f32_16x16x32_bf16(     \
          af[mi][kk], bf[(QN)*2 + ni][kk], acc[(QM)*4 + mi][(QN)*2 + ni], 0, 0, 0);

#define RDA(BB, QM)                                                                \
  _Pragma("unroll") for (int mi = 0; mi < 4; ++mi)                                 \
  _Pragma("unroll") for (int kk = 0; kk < 2; ++kk)                                 \
      af[mi][kk] = *(const bf16x8*)((const char*)&L[BB][0][0] +                    \
          ((abase + ((QM)*4 + mi) * 2048 + kk * 64) ^ xsw));

#define RDB(BB, QN)                                                                \
  _Pragma("unroll") for (int ni = 0; ni < 2; ++ni)                                 \
  _Pragma("unroll") for (int kk = 0; kk < 2; ++kk)                                 \
      bf[(QN)*2 + ni][kk] = *(const bf16x8*)((const char*)&L[BB][1][0] +           \
          ((bbase + ((QN)*2 + ni) * 2048 + kk * 64) ^ xsw));

#define BAR() __builtin_amdgcn_s_barrier()
#define LGKM0() asm volatile("s_waitcnt lgkmcnt(0)" ::: "memory")
#define PRIO1() __builtin_amdgcn_s_setprio(1)
#define PRIO0() __builtin_amdgcn_s_setprio(0)

template <int MODE>
__global__ __launch_bounds__(512, 2) void k_gemm(const u16* __restrict__ A,
                                                 const u16* __restrict__ Bt,
                                                 void* __restrict__ Cout) {
  __shared__ __align__(16) u16 L[2][2][16384];
  const int tid = threadIdx.x;
  const int wid = tid >> 6, lane = tid & 63;
  const int g = lane >> 4, li = lane & 15;
  const int wr = wid >> 2, wc = wid & 3;

  const int bid = blockIdx.x;
  const int sw = ((bid & 7) << 5) | (bid >> 3);
  const int brow = (sw >> 4) * 256, bcol = (sw & 15) * 256;

  const int xsw = (li & 7) << 4;
  const int abase = (wr * 128 + li) * 128 + g * 16;
  const int bbase = (wc * 64 + li) * 128 + g * 16;

  const int sxy = ((tid >> 3) & 7) << 3;
  const int scol = ((tid * 8) ^ sxy) & 63;
  const int srow0 = tid >> 3;

  auto STAGE = [&](int gidx) {
    if (gidx >= 4 * NT) return;
    const int t = gidx >> 2, h = gidx & 3;
    const int bb2 = t & 1;
    const int mat = h >> 1;
    const int half = h & 1;
    const u16* G = mat ? Bt : A;
    const int rowbase = (mat ? bcol : brow) + half * 128;
    const int k0 = t << 6;
    u16* Ld = &L[bb2][mat][half * 8192 + wid * 512];
    const u16* gsrc = G + (size_t)(rowbase + srow0) * DD + k0 + scol;
    gl_lds16(gsrc, Ld);
    gl_lds16(gsrc + (size_t)64 * DD, Ld + 4096);
  };

  f32x4 acc[8][4];
#pragma unroll
  for (int m = 0; m < 8; ++m)
#pragma unroll
    for (int n = 0; n < 4; ++n) acc[m][n] = zero4();

  bf16x8 af[4][2], bf[4][2];

#pragma unroll
  for (int gi = 0; gi < 5; ++gi) STAGE(gi);
  asm volatile("s_waitcnt vmcnt(2)" ::: "memory");
  BAR();

  for (int kt = 0; kt < NT; ++kt) {
    const int bb = kt & 1;
    const int gb = 4 * kt;
    RDA(bb, 0); RDB(bb, 0);
    STAGE(gb + 5);
    BAR(); LGKM0();
    PRIO1(); MFMA16(0, 0); PRIO0();
    BAR();
    RDB(bb, 1);
    STAGE(gb + 6);
    BAR(); LGKM0();
    PRIO1(); MFMA16(0, 1); PRIO0();
    BAR();
    RDA(bb, 1);
    STAGE(gb + 7);
    BAR(); LGKM0();
    PRIO1(); MFMA16(1, 0); PRIO0();
    BAR();
    STAGE(gb + 8);
    if (kt < NT - 2) {
      asm volatile("s_waitcnt vmcnt(2)" ::: "memory");
    } else {
      asm volatile("s_waitcnt vmcnt(0)" ::: "memory");
    }
    BAR(); LGKM0();
    PRIO1(); MFMA16(1, 1); PRIO0();
    BAR();
  }

#pragma unroll
  for (int m = 0; m < 8; ++m) {
#pragma unroll
    for (int n = 0; n < 4; ++n) {
#pragma unroll
      for (int r = 0; r < 4; ++r) {
        int row = brow + wr * 128 + m * 16 + g * 4 + r;
        int col = bcol + wc * 64 + n * 16 + li;
        float v = acc[m][n][r];
        if (MODE == 0) {
          ((u16*)Cout)[(size_t)row * DD + col] = f2bf(v);
        } else if (MODE == 1) {
          ((u16*)Cout)[((size_t)((row >> 11) << 12) + col) * SS + (row & 2047)] = f2bf(v);
        } else {
          ((float*)Cout)[(size_t)row * DD + col] = v;
        }
      }
    }
  }
}

// ---------------- RoPE in-place on Q and K ----------------
__global__ __launch_bounds__(256) void k_rope(u16* __restrict__ Q, u16* __restrict__ Kp,
                                              const float* __restrict__ fc,
                                              const float* __restrict__ fs) {
  int idx = blockIdx.x * blockDim.x + threadIdx.x;
  const int n8 = MM * DD / 8;
  u16* T = idx < n8 ? Q : Kp;
  int i = idx < n8 ? idx : idx - n8;
  int m = i >> 9;
  int c = (i & 511) * 8;
  int s = m & (SS - 1);
  int i0 = (c & (HDD - 1)) >> 1;
  size_t o = (size_t)m * DD + c;
  ushort8 v = *(ushort8*)(T + o);
  float4v cs = *(const float4v*)(fc + s * 64 + i0);
  float4v sn = *(const float4v*)(fs + s * 64 + i0);
  ushort8 ov;
#pragma unroll
  for (int p = 0; p < 4; ++p) {
    float a = bf2f(v[2 * p]), cc = bf2f(v[2 * p + 1]);
    ov[2 * p]     = f2bf(a * cs[p] - cc * sn[p]);
    ov[2 * p + 1] = f2bf(a * sn[p] + cc * cs[p]);
  }
  *(ushort8*)(T + o) = ov;
}

// ---------------- flash attention v2: QBLK=128, dbuf K/V, async-stage, heavy-first ----------------
__global__ __launch_bounds__(256, 2) void k_attn(const u16* __restrict__ Q,
                                                 const u16* __restrict__ K,
                                                 const u16* __restrict__ VT,
                                                 u16* __restrict__ O) {
  __shared__ __align__(16) u16 Kl[2][64 * 128];
  __shared__ __align__(16) u16 Vl[2][128 * 64];
  __shared__ __align__(16) u16 Pl[4][16 * 64];
  const int qt = 15 - blockIdx.x;  // heavy blocks dispatch first
  const int bh = blockIdx.y;
  const int b = bh >> 5, h = bh & 31;
  const int tid = threadIdx.x, w = tid >> 6, lane = tid & 63;
  const int g = lane >> 4, li = lane & 15;

  const u16* Qbase = Q + ((size_t)(b * SS + qt * 128 + w * 32)) * DD + h * HDD;
  const u16* Kbase = K + ((size_t)(b * SS)) * DD + h * HDD;
  const u16* Vbase = VT + ((size_t)bh) * HDD * SS;

  bf16x8 qf[2][4];
#pragma unroll
  for (int qm = 0; qm < 2; ++qm)
#pragma unroll
    for (int ks = 0; ks < 4; ++ks)
      qf[qm][ks] = *(const bf16x8*)(Qbase + (size_t)(qm * 16 + li) * DD + ks * 32 + g * 8);

  f32x4 oa[2][8];
#pragma unroll
  for (int qm = 0; qm < 2; ++qm)
#pragma unroll
    for (int f = 0; f < 8; ++f) oa[qm][f] = zero4();
  float mrun[2][4], lrun[2][4];
#pragma unroll
  for (int qm = 0; qm < 2; ++qm)
#pragma unroll
    for (int r = 0; r < 4; ++r) { mrun[qm][r] = -1e30f; lrun[qm][r] = 0.f; }

  const float sc2 = 0.08838834764831845f * 1.44269504088896340f;  // 1/sqrt(128)*log2e
  const int ktmax = 2 * qt + 1;

  // prologue: stage tile 0 into buf 0
  {
#pragma unroll
    for (int i = 0; i < 4; ++i) {
      int e = tid + i * 256;
      int kr = e >> 4, dc = e & 15;
      uint4v kv = *(const uint4v*)(Kbase + (size_t)kr * DD + dc * 8);
      *(uint4v*)((char*)Kl[0] + ((kr * 256 + dc * 16) ^ ((kr & 7) << 4))) = kv;
      int dr = e >> 3, kc = e & 7;
      uint4v vv = *(const uint4v*)(Vbase + (size_t)dr * SS + kc * 8);
      *(uint4v*)((char*)Vl[0] + ((dr * 128 + kc * 16) ^ ((dr & 7) << 4))) = vv;
    }
  }
  __syncthreads();

  for (int kt = 0; kt <= ktmax; ++kt) {
    const int cur = kt & 1;
    const bool pf = kt < ktmax;
    uint4v kreg[4], vreg[4];
    if (pf) {  // T14: issue next-tile loads early; consume after compute
      const u16* Kt = Kbase + (size_t)((kt + 1) * 64) * DD;
      const u16* Vt = Vbase + (kt + 1) * 64;
#pragma unroll
      for (int i = 0; i < 4; ++i) {
        int e = tid + i * 256;
        kreg[i] = *(const uint4v*)(Kt + (size_t)(e >> 4) * DD + (e & 15) * 8);
        vreg[i] = *(const uint4v*)(Vt + (size_t)(e >> 3) * SS + (e & 7) * 8);
      }
    }
    const char* Kb = (const char*)Kl[cur];
    const char* Vb = (const char*)Vl[cur];
    const int kg0 = kt * 64;

#pragma unroll
    for (int qm = 0; qm < 2; ++qm) {
      // QK^T: 16 q-rows x 64 k-cols
      f32x4 sc[4];
#pragma unroll
      for (int ni = 0; ni < 4; ++ni) sc[ni] = zero4();
      PRIO1();
#pragma unroll
      for (int ks = 0; ks < 4; ++ks) {
#pragma unroll
        for (int ni = 0; ni < 4; ++ni) {
          int kr = ni * 16 + li;
          int off = (kr * 256 + (ks * 32 + g * 8) * 2) ^ ((kr & 7) << 4);
          bf16x8 kf = *(const bf16x8*)(Kb + off);
          sc[ni] = __builtin_amdgcn_mfma_f32_16x16x32_bf16(qf[qm][ks], kf, sc[ni], 0, 0, 0);
        }
      }
      PRIO0();

      // online softmax
      float pb[16], alpha[4];
      const int qrow = qt * 128 + w * 32 + qm * 16 + g * 4;
#pragma unroll
      for (int r = 0; r < 4; ++r) {
        float t = -1e30f;
#pragma unroll
        for (int ni = 0; ni < 4; ++ni) {
          float s = sc[ni][r] * sc2;
          int kc = kg0 + ni * 16 + li;
          if (kc > qrow + r) s = -1e30f;
          pb[ni * 4 + r] = s;
          t = fmaxf(t, s);
        }
        t = fmaxf(t, __shfl_xor(t, 1));
        t = fmaxf(t, __shfl_xor(t, 2));
        t = fmaxf(t, __shfl_xor(t, 4));
        t = fmaxf(t, __shfl_xor(t, 8));
        float mnew = fmaxf(mrun[qm][r], t);
        alpha[r] = exp2f(mrun[qm][r] - mnew);
        mrun[qm][r] = mnew;
        float su = 0.f;
#pragma unroll
        for (int ni = 0; ni < 4; ++ni) {
          float pv = exp2f(pb[ni * 4 + r] - mnew);
          pb[ni * 4 + r] = pv;
          su += pv;
        }
        su += __shfl_xor(su, 1);
        su += __shfl_xor(su, 2);
        su += __shfl_xor(su, 4);
        su += __shfl_xor(su, 8);
        lrun[qm][r] = lrun[qm][r] * alpha[r] + su;
      }

      // P -> LDS (per-wave region, reused across qm; same-wave DS is in-order)
      {
        char* Pb = (char*)Pl[w];
#pragma unroll
        for (int r = 0; r < 4; ++r) {
          int qr = g * 4 + r;
          int sw2 = (qr & 7) << 4;
#pragma unroll
          for (int ni = 0; ni < 4; ++ni) {
            int off = (qr * 128 + (ni * 16 + li) * 2) ^ sw2;
            *(u16*)(Pb + off) = f2bf(pb[ni * 4 + r]);
          }
        }
      }
      asm volatile("s_waitcnt lgkmcnt(0)" ::: "memory");

      // rescale running accumulator
#pragma unroll
      for (int f = 0; f < 8; ++f)
#pragma unroll
        for (int r = 0; r < 4; ++r) oa[qm][f][r] *= alpha[r];

      // PV
      PRIO1();
#pragma unroll
      for (int ks2 = 0; ks2 < 2; ++ks2) {
        int poff = (li * 128 + (ks2 * 32 + g * 8) * 2) ^ ((li & 7) << 4);
        bf16x8 pfrag = *(const bf16x8*)((const char*)Pl[w] + poff);
#pragma unroll
        for (int f = 0; f < 8; ++f) {
          int dr = f * 16 + li;
          int voff = (dr * 128 + (ks2 * 32 + g * 8) * 2) ^ ((dr & 7) << 4);
          bf16x8 vf = *(const bf16x8*)(Vb + voff);
          oa[qm][f] = __builtin_amdgcn_mfma_f32_16x16x32_bf16(pfrag, vf, oa[qm][f], 0, 0, 0);
        }
      }
      PRIO0();
    }

    __syncthreads();  // all waves done reading buf[cur^1] (>=1 iter ago) and buf[cur]
    if (pf) {
      const int nb = cur ^ 1;
#pragma unroll
      for (int i = 0; i < 4; ++i) {
        int e = tid + i * 256;
        int kr = e >> 4, dc = e & 15;
        *(uint4v*)((char*)Kl[nb] + ((kr * 256 + dc * 16) ^ ((kr & 7) << 4))) = kreg[i];
        int dr = e >> 3, kc = e & 7;
        *(uint4v*)((char*)Vl[nb] + ((dr * 128 + kc * 16) ^ ((dr & 7) << 4))) = vreg[i];
      }
    }
    __syncthreads();  // next-tile LDS visible
  }

#pragma unroll
  for (int qm = 0; qm < 2; ++qm) {
    u16* Ob = O + ((size_t)(b * SS + qt * 128 + w * 32 + qm * 16 + g * 4)) * DD + h * HDD;
#pragma unroll
    for (int r = 0; r < 4; ++r) {
      float inv = 1.f / lrun[qm][r];
#pragma unroll
      for (int f = 0; f < 8; ++f)
        Ob[(size_t)r * DD + f * 16 + li] = f2bf(oa[qm][f][r] * inv);
    }
  }
}

// ---------------- host ----------------
extern "C" void kernel_launch(void* const* d_in, const int* in_sizes, int n_in,
                              void* d_out, int out_size, void* d_ws, size_t ws_size,
                              hipStream_t stream) {
  (void)in_sizes; (void)n_in; (void)out_size; (void)ws_size;
  const float* x    = (const float*)d_in[0];
  const float* Wq   = (const float*)d_in[1];
  const float* Wk   = (const float*)d_in[2];
  const float* Wv   = (const float*)d_in[3];
  const float* Wo   = (const float*)d_in[4];
  const float* fcos = (const float*)d_in[5];
  const float* fsin = (const float*)d_in[6];

  u16* ws = (u16*)d_ws;
  const size_t MAT = (size_t)4096 * 4096;
  u16* xb    = ws + 0 * MAT;
  u16* wqt   = ws + 1 * MAT;
  u16* wkt   = ws + 2 * MAT;
  u16* wvt   = ws + 3 * MAT;
  u16* wot   = ws + 4 * MAT;
  u16* Qb    = ws + 5 * MAT;
  u16* Kb    = ws + 6 * MAT;
  u16* VTb   = ws + 7 * MAT;
  u16* attnb = ws + 8 * MAT;

  k_cvt<<<dim3(8192), dim3(256), 0, stream>>>(x, xb, (int)(MAT / 8));
  k_wt<<<dim3(64, 64, 4), dim3(64, 4), 0, stream>>>(Wq, Wk, Wv, Wo, wqt);
  k_gemm<0><<<dim3(256), dim3(512), 0, stream>>>(xb, wqt, (void*)Qb);
  k_gemm<0><<<dim3(256), dim3(512), 0, stream>>>(xb, wkt, (void*)Kb);
  k_gemm<1><<<dim3(256), dim3(512), 0, stream>>>(xb, wvt, (void*)VTb);
  k_rope<<<dim3(16384), dim3(256), 0, stream>>>(Qb, Kb, fcos, fsin);
  k_attn<<<dim3(16, 64), dim3(256), 0, stream>>>(Qb, Kb, VTb, attnb);
  k_gemm<2><<<dim3(256), dim3(512), 0, stream>>>(attnb, wot, d_out);
}

// Round 4
// 950.859 us; speedup vs baseline: 1.3764x; 1.3764x over previous
//
#include <hip/hip_runtime.h>
#include <hip/hip_bf16.h>

#define DD 4096
#define MM 4096
#define SS 2048
#define HH 32
#define HDD 128
#define NT 64  // GEMM K-tiles of 64

typedef unsigned short u16;
typedef __attribute__((ext_vector_type(8))) __bf16 bf16x8;
typedef __attribute__((ext_vector_type(4))) float f32x4;
typedef __attribute__((ext_vector_type(4))) float float4v;
typedef __attribute__((ext_vector_type(8))) unsigned short ushort8;
typedef __attribute__((ext_vector_type(4))) unsigned int uint4v;

__device__ __forceinline__ u16 f2bf(float f) {
  union { float f; unsigned u; } v; v.f = f;
  unsigned u = v.u;
  return (u16)((u + 0x7fffu + ((u >> 16) & 1u)) >> 16);
}
__device__ __forceinline__ float bf2f(u16 s) {
  union { unsigned u; float f; } v; v.u = ((unsigned)s) << 16;
  return v.f;
}
__device__ __forceinline__ f32x4 zero4() { f32x4 z = {0.f, 0.f, 0.f, 0.f}; return z; }

__device__ __forceinline__ void gl_lds16(const u16* g, u16* l) {
  __builtin_amdgcn_global_load_lds((__attribute__((address_space(1))) void*)(g),
                                   (__attribute__((address_space(3))) void*)(l), 16, 0, 0);
}

// ---------------- f32 -> bf16 convert (x) ----------------
__global__ __launch_bounds__(256) void k_cvt(const float* __restrict__ in,
                                             u16* __restrict__ out, int n8) {
  int i = blockIdx.x * blockDim.x + threadIdx.x;
  if (i >= n8) return;
  size_t o = (size_t)i * 8;
  float4v a = *(const float4v*)(in + o);
  float4v b = *(const float4v*)(in + o + 4);
  ushort8 v;
  v[0] = f2bf(a[0]); v[1] = f2bf(a[1]); v[2] = f2bf(a[2]); v[3] = f2bf(a[3]);
  v[4] = f2bf(b[0]); v[5] = f2bf(b[1]); v[6] = f2bf(b[2]); v[7] = f2bf(b[3]);
  *(ushort8*)(out + o) = v;
}

// ---------------- weight transpose + convert: out[n][k] = W[k][n] ----------------
__global__ __launch_bounds__(256) void k_wt(const float* __restrict__ W0,
                                            const float* __restrict__ W1,
                                            const float* __restrict__ W2,
                                            const float* __restrict__ W3,
                                            u16* __restrict__ out) {
  const float* W = blockIdx.z == 0 ? W0 : blockIdx.z == 1 ? W1 : blockIdx.z == 2 ? W2 : W3;
  u16* O = out + (size_t)blockIdx.z * DD * DD;
  __shared__ u16 t[64][65];
  int k0 = blockIdx.x * 64, n0 = blockIdx.y * 64;
  int tx = threadIdx.x, ty = threadIdx.y;  // (64,4)
#pragma unroll
  for (int i = 0; i < 16; ++i) {
    int kk = ty + i * 4;
    t[tx][kk] = f2bf(W[(size_t)(k0 + kk) * DD + n0 + tx]);
  }
  __syncthreads();
#pragma unroll
  for (int i = 0; i < 16; ++i) {
    int nn = ty + i * 4;
    O[(size_t)(n0 + nn) * DD + k0 + tx] = t[nn][tx];
  }
}

// ---------------- 256x256 8-phase bf16 GEMM (m201 template) ----------------
#define MFMA16(QM, QN)                                                             \
  _Pragma("unroll") for (int kk = 0; kk < 2; ++kk)                                 \
  _Pragma("unroll") for (int mi = 0; mi < 4; ++mi)                                 \
  _Pragma("unroll") for (int ni = 0; ni < 2; ++ni)                                 \
      acc[(QM)*4 + mi][(QN)*2 + ni] = __builtin_amdgcn_mfma_f32_16x16x32_bf16(     \
          af[mi][kk], bf[(QN)*2 + ni][kk], acc[(QM)*4 + mi][(QN)*2 + ni], 0, 0, 0);

#define RDA(BB, QM)                                                                \
  _Pragma("unroll") for (int mi = 0; mi < 4; ++mi)                                 \
  _Pragma("unroll") for (int kk = 0; kk < 2; ++kk)                                 \
      af[mi][kk] = *(const bf16x8*)((const char*)&L[BB][0][0] +                    \
          ((abase + ((QM)*4 + mi) * 2048 + kk * 64) ^ xsw));

#define RDB(BB, QN)                                                                \
  _Pragma("unroll") for (int ni = 0; ni < 2; ++ni)                                 \
  _Pragma("unroll") for (int kk = 0; kk < 2; ++kk)                                 \
      bf[(QN)*2 + ni][kk] = *(const bf16x8*)((const char*)&L[BB][1][0] +           \
          ((bbase + ((QN)*2 + ni) * 2048 + kk * 64) ^ xsw));

#define BAR() __builtin_amdgcn_s_barrier()
#define LGKM0() asm volatile("s_waitcnt lgkmcnt(0)" ::: "memory")
#define PRIO1() __builtin_amdgcn_s_setprio(1)
#define PRIO0() __builtin_amdgcn_s_setprio(0)

template <int MODE>
__global__ __launch_bounds__(512, 2) void k_gemm(const u16* __restrict__ A,
                                                 const u16* __restrict__ Bt,
                                                 void* __restrict__ Cout) {
  __shared__ __align__(16) u16 L[2][2][16384];
  const int tid = threadIdx.x;
  const int wid = tid >> 6, lane = tid & 63;
  const int g = lane >> 4, li = lane & 15;
  const int wr = wid >> 2, wc = wid & 3;

  const int bid = blockIdx.x;
  const int sw = ((bid & 7) << 5) | (bid >> 3);
  const int brow = (sw >> 4) * 256, bcol = (sw & 15) * 256;

  const int xsw = (li & 7) << 4;
  const int abase = (wr * 128 + li) * 128 + g * 16;
  const int bbase = (wc * 64 + li) * 128 + g * 16;

  const int sxy = ((tid >> 3) & 7) << 3;
  const int scol = ((tid * 8) ^ sxy) & 63;
  const int srow0 = tid >> 3;

  auto STAGE = [&](int gidx) {
    if (gidx >= 4 * NT) return;
    const int t = gidx >> 2, h = gidx & 3;
    const int bb2 = t & 1;
    const int mat = h >> 1;
    const int half = h & 1;
    const u16* G = mat ? Bt : A;
    const int rowbase = (mat ? bcol : brow) + half * 128;
    const int k0 = t << 6;
    u16* Ld = &L[bb2][mat][half * 8192 + wid * 512];
    const u16* gsrc = G + (size_t)(rowbase + srow0) * DD + k0 + scol;
    gl_lds16(gsrc, Ld);
    gl_lds16(gsrc + (size_t)64 * DD, Ld + 4096);
  };

  f32x4 acc[8][4];
#pragma unroll
  for (int m = 0; m < 8; ++m)
#pragma unroll
    for (int n = 0; n < 4; ++n) acc[m][n] = zero4();

  bf16x8 af[4][2], bf[4][2];

#pragma unroll
  for (int gi = 0; gi < 5; ++gi) STAGE(gi);
  asm volatile("s_waitcnt vmcnt(2)" ::: "memory");
  BAR();

  for (int kt = 0; kt < NT; ++kt) {
    const int bb = kt & 1;
    const int gb = 4 * kt;
    RDA(bb, 0); RDB(bb, 0);
    STAGE(gb + 5);
    BAR(); LGKM0();
    PRIO1(); MFMA16(0, 0); PRIO0();
    BAR();
    RDB(bb, 1);
    STAGE(gb + 6);
    BAR(); LGKM0();
    PRIO1(); MFMA16(0, 1); PRIO0();
    BAR();
    RDA(bb, 1);
    STAGE(gb + 7);
    BAR(); LGKM0();
    PRIO1(); MFMA16(1, 0); PRIO0();
    BAR();
    STAGE(gb + 8);
    if (kt < NT - 2) {
      asm volatile("s_waitcnt vmcnt(2)" ::: "memory");
    } else {
      asm volatile("s_waitcnt vmcnt(0)" ::: "memory");
    }
    BAR(); LGKM0();
    PRIO1(); MFMA16(1, 1); PRIO0();
    BAR();
  }

#pragma unroll
  for (int m = 0; m < 8; ++m) {
#pragma unroll
    for (int n = 0; n < 4; ++n) {
#pragma unroll
      for (int r = 0; r < 4; ++r) {
        int row = brow + wr * 128 + m * 16 + g * 4 + r;
        int col = bcol + wc * 64 + n * 16 + li;
        float v = acc[m][n][r];
        if (MODE == 0) {
          ((u16*)Cout)[(size_t)row * DD + col] = f2bf(v);
        } else if (MODE == 1) {
          ((u16*)Cout)[((size_t)((row >> 11) << 12) + col) * SS + (row & 2047)] = f2bf(v);
        } else {
          ((float*)Cout)[(size_t)row * DD + col] = v;
        }
      }
    }
  }
}

// ---------------- RoPE in-place on Q and K ----------------
__global__ __launch_bounds__(256) void k_rope(u16* __restrict__ Q, u16* __restrict__ Kp,
                                              const float* __restrict__ fc,
                                              const float* __restrict__ fs) {
  int idx = blockIdx.x * blockDim.x + threadIdx.x;
  const int n8 = MM * DD / 8;
  u16* T = idx < n8 ? Q : Kp;
  int i = idx < n8 ? idx : idx - n8;
  int m = i >> 9;
  int c = (i & 511) * 8;
  int s = m & (SS - 1);
  int i0 = (c & (HDD - 1)) >> 1;
  size_t o = (size_t)m * DD + c;
  ushort8 v = *(ushort8*)(T + o);
  float4v cs = *(const float4v*)(fc + s * 64 + i0);
  float4v sn = *(const float4v*)(fs + s * 64 + i0);
  ushort8 ov;
#pragma unroll
  for (int p = 0; p < 4; ++p) {
    float a = bf2f(v[2 * p]), cc = bf2f(v[2 * p + 1]);
    ov[2 * p]     = f2bf(a * cs[p] - cc * sn[p]);
    ov[2 * p + 1] = f2bf(a * sn[p] + cc * cs[p]);
  }
  *(ushort8*)(T + o) = ov;
}

// ---------------- flash attention v3: swapped QK^T, lane-parallel softmax ----------------
// Round-2 shell (single-buffer, 40KB LDS, 4 blocks/CU) + mfma(K,Q) so each lane
// owns one q-row's scores (q = li); softmax reduce = 2 shfl_xor; scalar m/l state.
__global__ __launch_bounds__(256) void k_attn(const u16* __restrict__ Q,
                                              const u16* __restrict__ K,
                                              const u16* __restrict__ VT,
                                              u16* __restrict__ O) {
  __shared__ __align__(16) u16 Kl[64 * 128];
  __shared__ __align__(16) u16 Vl[128 * 64];
  __shared__ __align__(16) u16 Pl[4][16 * 64];
  const int qt = 31 - blockIdx.x;  // heavy blocks dispatch first
  const int bh = blockIdx.y;
  const int b = bh >> 5, h = bh & 31;
  const int tid = threadIdx.x, w = tid >> 6, lane = tid & 63;
  const int g = lane >> 4, li = lane & 15;

  const u16* Qbase = Q + ((size_t)(b * SS + qt * 64)) * DD + h * HDD;
  const u16* Kbase = K + ((size_t)(b * SS)) * DD + h * HDD;
  const u16* Vbase = VT + ((size_t)bh) * HDD * SS;

  // Q B-frag: lane holds Q[q = w*16+li][d = ks*32 + g*8 + 0..7]
  bf16x8 qf[4];
#pragma unroll
  for (int ks = 0; ks < 4; ++ks)
    qf[ks] = *(const bf16x8*)(Qbase + (size_t)(w * 16 + li) * DD + ks * 32 + g * 8);

  f32x4 oa[8];
#pragma unroll
  for (int f = 0; f < 8; ++f) oa[f] = zero4();
  float mrun = -1e30f, lrun = 0.f;  // scalar state for q = w*16 + li

  const float sc2 = 0.08838834764831845f * 1.44269504088896340f;  // 1/sqrt(128)*log2e
  const int qg = qt * 64 + w * 16 + li;  // this lane's q row (softmax view)

  for (int kt = 0; kt <= qt; ++kt) {
    __syncthreads();
    const u16* Kt = Kbase + (size_t)(kt * 64) * DD;
    const u16* Vt = Vbase + kt * 64;
#pragma unroll
    for (int i = 0; i < 4; ++i) {
      int cc = tid + i * 256;
      int kr = cc >> 4, dc = cc & 15;
      uint4v kv = *(const uint4v*)(Kt + (size_t)kr * DD + dc * 8);
      *(uint4v*)((char*)Kl + ((kr * 256 + dc * 16) ^ ((kr & 7) << 4))) = kv;
      int dr = cc >> 3, kc2 = cc & 7;
      uint4v vv = *(const uint4v*)(Vt + (size_t)dr * SS + kc2 * 8);
      *(uint4v*)((char*)Vl + ((dr * 128 + kc2 * 16) ^ ((dr & 7) << 4))) = vv;
    }
    __syncthreads();

    // swapped QK^T: S[k][q] = mfma(K_frag, Q_frag); sc[ktg][r] = S[kt*64+ktg*16+g*4+r][li]
    f32x4 sc[4];
#pragma unroll
    for (int ktg = 0; ktg < 4; ++ktg) sc[ktg] = zero4();
    PRIO1();
#pragma unroll
    for (int ks = 0; ks < 4; ++ks) {
#pragma unroll
      for (int ktg = 0; ktg < 4; ++ktg) {
        int kr = ktg * 16 + li;
        int off = (kr * 256 + (ks * 32 + g * 8) * 2) ^ ((kr & 7) << 4);
        bf16x8 kf = *(const bf16x8*)((const char*)Kl + off);
        sc[ktg] = __builtin_amdgcn_mfma_f32_16x16x32_bf16(kf, qf[ks], sc[ktg], 0, 0, 0);
      }
    }
    PRIO0();

    // lane-parallel online softmax (each lane: one q, 16 of 64 k)
    float p[16];
    float tmax = -1e30f;
    const int kb = kt * 64 + g * 4;
#pragma unroll
    for (int ktg = 0; ktg < 4; ++ktg) {
#pragma unroll
      for (int r = 0; r < 4; ++r) {
        float s = sc[ktg][r] * sc2;
        if (kb + ktg * 16 + r > qg) s = -1e30f;
        p[ktg * 4 + r] = s;
        tmax = fmaxf(tmax, s);
      }
    }
    tmax = fmaxf(tmax, __shfl_xor(tmax, 16));
    tmax = fmaxf(tmax, __shfl_xor(tmax, 32));
    float mnew = fmaxf(mrun, tmax);
    float alpha = exp2f(mrun - mnew);
    mrun = mnew;
    float su = 0.f;
#pragma unroll
    for (int i = 0; i < 16; ++i) {
      p[i] = exp2f(p[i] - mnew);
      su += p[i];
    }
    su += __shfl_xor(su, 16);
    su += __shfl_xor(su, 32);
    lrun = lrun * alpha + su;

    // P -> LDS: row q=li, cols k = ktg*16 + g*4 + {0..3}, packed pairs (2-way conflict = free)
    {
      char* Pb = (char*)Pl[w];
      const int swz = (li & 7) << 4;
#pragma unroll
      for (int ktg = 0; ktg < 4; ++ktg) {
#pragma unroll
        for (int j = 0; j < 2; ++j) {
          unsigned pk = (unsigned)f2bf(p[ktg * 4 + 2 * j]) |
                        ((unsigned)f2bf(p[ktg * 4 + 2 * j + 1]) << 16);
          int off = (li * 128 + (ktg * 16 + g * 4 + 2 * j) * 2) ^ swz;
          *(unsigned*)(Pb + off) = pk;
        }
      }
    }
    asm volatile("s_waitcnt lgkmcnt(0)" ::: "memory");

    // rescale accumulator: oa rows are q = g*4 + r -> fetch those lanes' alpha
    float av[4];
#pragma unroll
    for (int r = 0; r < 4; ++r) av[r] = __shfl(alpha, g * 20 + r);
#pragma unroll
    for (int f = 0; f < 8; ++f)
#pragma unroll
      for (int r = 0; r < 4; ++r) oa[f][r] *= av[r];

    // PV: O[16q][128d] += P[16q][64k] * V[64k][128d]
    PRIO1();
#pragma unroll
    for (int ks2 = 0; ks2 < 2; ++ks2) {
      int poff = (li * 128 + (ks2 * 32 + g * 8) * 2) ^ ((li & 7) << 4);
      bf16x8 pfrag = *(const bf16x8*)((const char*)Pl[w] + poff);
#pragma unroll
      for (int f = 0; f < 8; ++f) {
        int dr = f * 16 + li;
        int voff = (dr * 128 + (ks2 * 32 + g * 8) * 2) ^ ((dr & 7) << 4);
        bf16x8 vf = *(const bf16x8*)((const char*)Vl + voff);
        oa[f] = __builtin_amdgcn_mfma_f32_16x16x32_bf16(pfrag, vf, oa[f], 0, 0, 0);
      }
    }
    PRIO0();
  }

  // epilogue: O rows q = g*4 + r; fetch l from the lane that owns that q
  float lv[4];
#pragma unroll
  for (int r = 0; r < 4; ++r) lv[r] = __shfl(lrun, g * 20 + r);
  u16* Ob = O + ((size_t)(b * SS + qt * 64 + w * 16 + g * 4)) * DD + h * HDD;
#pragma unroll
  for (int r = 0; r < 4; ++r) {
    float inv = 1.f / lv[r];
#pragma unroll
    for (int f = 0; f < 8; ++f)
      Ob[(size_t)r * DD + f * 16 + li] = f2bf(oa[f][r] * inv);
  }
}

// ---------------- host ----------------
extern "C" void kernel_launch(void* const* d_in, const int* in_sizes, int n_in,
                              void* d_out, int out_size, void* d_ws, size_t ws_size,
                              hipStream_t stream) {
  (void)in_sizes; (void)n_in; (void)out_size; (void)ws_size;
  const float* x    = (const float*)d_in[0];
  const float* Wq   = (const float*)d_in[1];
  const float* Wk   = (const float*)d_in[2];
  const float* Wv   = (const float*)d_in[3];
  const float* Wo   = (const float*)d_in[4];
  const float* fcos = (const float*)d_in[5];
  const float* fsin = (const float*)d_in[6];

  u16* ws = (u16*)d_ws;
  const size_t MAT = (size_t)4096 * 4096;
  u16* xb    = ws + 0 * MAT;
  u16* wqt   = ws + 1 * MAT;
  u16* wkt   = ws + 2 * MAT;
  u16* wvt   = ws + 3 * MAT;
  u16* wot   = ws + 4 * MAT;
  u16* Qb    = ws + 5 * MAT;
  u16* Kb    = ws + 6 * MAT;
  u16* VTb   = ws + 7 * MAT;
  u16* attnb = ws + 8 * MAT;

  k_cvt<<<dim3(8192), dim3(256), 0, stream>>>(x, xb, (int)(MAT / 8));
  k_wt<<<dim3(64, 64, 4), dim3(64, 4), 0, stream>>>(Wq, Wk, Wv, Wo, wqt);
  k_gemm<0><<<dim3(256), dim3(512), 0, stream>>>(xb, wqt, (void*)Qb);
  k_gemm<0><<<dim3(256), dim3(512), 0, stream>>>(xb, wkt, (void*)Kb);
  k_gemm<1><<<dim3(256), dim3(512), 0, stream>>>(xb, wvt, (void*)VTb);
  k_rope<<<dim3(16384), dim3(256), 0, stream>>>(Qb, Kb, fcos, fsin);
  k_attn<<<dim3(32, 64), dim3(256), 0, stream>>>(Qb, Kb, VTb, attnb);
  k_gemm<2><<<dim3(256), dim3(512), 0, stream>>>(attnb, wot, d_out);
}